// Round 6
// baseline (538.588 us; speedup 1.0000x reference)
//
#include <hip/hip_runtime.h>
#include <math.h>

typedef __attribute__((ext_vector_type(8))) short bf16x8;
typedef __attribute__((ext_vector_type(4))) float f32x4;

union B8 { bf16x8 v; unsigned u[4]; };

__device__ __forceinline__ unsigned pk2(float lo, float hi) {
  unsigned r;
  asm("v_cvt_pk_bf16_f32 %0, %1, %2" : "=v"(r) : "v"(lo), "v"(hi));
  return r;
}
__device__ __forceinline__ float rcpf(float x) { return __builtin_amdgcn_rcpf(x); }
__device__ __forceinline__ void ldsfence() { asm volatile("s_waitcnt lgkmcnt(0)" ::: "memory"); }

#define MFMA __builtin_amdgcn_mfma_f32_16x16x32_bf16

// ---------------- prep: Kopen pack [0..1023], symA [1024..1312], sumA2 [1313], k0sq [1320..1383]
__global__ void otflow_prep(const float* __restrict__ K0g,
                            const float* __restrict__ Ag,
                            float* __restrict__ ws) {
  __shared__ float Als[170];
  int tid = threadIdx.x;
  for (int idx = tid; idx < 1024; idx += 256) {
    int m = idx >> 4, d = idx & 15;
    ws[idx] = K0g[m * 17 + d];
  }
  if (tid < 170) Als[tid] = Ag[tid];
  if (tid < 64) {
    float s = 0.f;
    for (int d = 0; d < 16; ++d) { float v = K0g[tid * 17 + d]; s += v * v; }
    ws[1320 + tid] = s;
  }
  __syncthreads();
  for (int idx = tid; idx < 289; idx += 256) {
    int j = idx / 17, k2 = idx % 17;
    float s = 0.f;
#pragma unroll
    for (int r = 0; r < 10; ++r) s += Als[r * 17 + j] * Als[r * 17 + k2];
    ws[1024 + idx] = s;
  }
  __syncthreads();
  if (tid == 0) {
    float s = 0.f;
    for (int r = 0; r < 10; ++r)
      for (int j = 0; j < 16; ++j) { float v = Als[r * 17 + j]; s += v * v; }
    ws[1313] = s;
  }
}

// ---------------- main: 2 waves cooperate on 16 particles (batched in MFMA N dim)
__global__ __launch_bounds__(128, 2) void otflow_main(
    const float* __restrict__ xg, const float* __restrict__ wg,
    const float* __restrict__ bg, const float* __restrict__ K0g,
    const float* __restrict__ b0g, const float* __restrict__ K1g,
    const float* __restrict__ b1g, const int* __restrict__ ntg,
    const float* __restrict__ ws, float* __restrict__ out, int n) {
  __shared__ float Xb[16 * 68];   // u0 (F1..F2), then rv (F3..F4)
  __shared__ float Yb[16 * 68];   // S bounce (pre-F1), then a (F2..F3)
  __shared__ float csh[16 * 68];  // c (F1..F4)
  __shared__ float qsh[16 * 68];  // q (F2..F4)
  __shared__ float gsh[16 * 20];  // g0 rows (F4..)
  __shared__ float tsh[16];       // per-particle t1 totals (full-wave butterfly)
  __shared__ float b0s[64], tcs[64], b1s[64], wss[64], k0qs[64];
  __shared__ float trhs[32], gsh2[16];

  const int tid = threadIdx.x;
  const int wid = tid >> 6;
  const int lane = tid & 63;
  const int lr = lane & 15;
  const int lg = lane >> 4;

  if (wid == 0) {
    b0s[lane] = b0g[lane];
    tcs[lane] = K0g[lane * 17 + 16];
    b1s[lane] = b1g[lane];
    wss[lane] = wg[lane];
    k0qs[lane] = ws[1320 + lane];
  }

  const float sumA2 = ws[1313];

  // ---- const fragments ----
  B8 aK0h[2], aK0l[2];          // opening rows (2w+t)*16.., hi/lo split, dup over k-halves
#pragma unroll
  for (int t = 0; t < 2; ++t) {
    int R = (2 * wid + t) * 16 + lr;
    B8 th, tl;
#pragma unroll
    for (int jj = 0; jj < 4; ++jj) {
      float e0 = K0g[R * 17 + (lg & 1) * 8 + jj * 2];
      float e1 = K0g[R * 17 + (lg & 1) * 8 + jj * 2 + 1];
      unsigned hh = pk2(e0, e1);
      th.u[jj] = hh;
      float l0 = e0 - __uint_as_float(hh << 16);
      float l1 = e1 - __uint_as_float(hh & 0xffff0000u);
      tl.u[jj] = pk2(l0, l1);
    }
    aK0h[t] = th; aK0l[t] = tl;
  }
  B8 aK1[8];                     // K1 row-blocks (full; A for feat1-own, B for KJ)
#pragma unroll
  for (int mi = 0; mi < 4; ++mi)
#pragma unroll
    for (int kb = 0; kb < 2; ++kb) {
      const float* pp = K1g + (mi * 16 + lr) * 64 + kb * 32 + lg * 8;
      float4 q0 = *(const float4*)pp;
      float4 q1 = *(const float4*)(pp + 4);
      B8 t;
      t.u[0] = pk2(q0.x, q0.y); t.u[1] = pk2(q0.z, q0.w);
      t.u[2] = pk2(q1.x, q1.y); t.u[3] = pk2(q1.z, q1.w);
      aK1[mi * 2 + kb] = t;
    }
  B8 aK1T[4];                    // K1^T rows (2w+t)*16.. (z1)
#pragma unroll
  for (int t = 0; t < 2; ++t)
#pragma unroll
    for (int kb = 0; kb < 2; ++kb) {
      int ib = kb * 32 + lg * 8;
      int m = (2 * wid + t) * 16 + lr;
      B8 tt;
#pragma unroll
      for (int jj = 0; jj < 4; ++jj)
        tt.u[jj] = pk2(K1g[(ib + jj * 2) * 64 + m], K1g[(ib + jj * 2 + 1) * 64 + m]);
      aK1T[t * 2 + kb] = tt;
    }
  B8 aG[3];                      // grad tile nb=wid: [K0 | symA | b], K=96
  {
    int j = wid * 16 + lr; if (j > 16) j = 16;
#pragma unroll
    for (int kb = 0; kb < 3; ++kb) {
      float e[8];
#pragma unroll
      for (int jj = 0; jj < 8; ++jj) {
        float v;
        if (kb < 2) v = K0g[(kb * 32 + lg * 8 + jj) * 17 + j];
        else {
          int kr = lg * 8 + jj;
          v = (kr < 17) ? ws[1024 + kr * 17 + j] : (kr == 17) ? bg[j] : 0.f;
        }
        e[jj] = v;
      }
      B8 t;
      t.u[0] = pk2(e[0], e[1]); t.u[1] = pk2(e[2], e[3]);
      t.u[2] = pk2(e[4], e[5]); t.u[3] = pk2(e[6], e[7]);
      aG[kb] = t;
    }
  }
  float kop[16];                 // Kopen[m][lr], m = kb*32+lg*8+j
#pragma unroll
  for (int kb = 0; kb < 2; ++kb)
#pragma unroll
    for (int j = 0; j < 8; ++j)
      kop[kb * 8 + j] = ws[(kb * 32 + lg * 8 + j) * 16 + lr];

  __syncthreads();

  const int nt = *ntg;
  const float h = 1.0f / (float)nt;
  const int p0 = blockIdx.x * 16;
  int pidx = p0 + lr; if (pidx >= n) pidx = n - 1;

  float xin[4], x0s[4], xac[4];
  {
    float4 xi = *(const float4*)(xg + (size_t)pidx * 16 + lg * 4);
    xin[0] = xi.x; xin[1] = xi.y; xin[2] = xi.z; xin[3] = xi.w;
#pragma unroll
    for (int r = 0; r < 4; ++r) { x0s[r] = xin[r]; xac[r] = xin[r]; }
  }
  float lacc = 0.f, vacc = 0.f, racc = 0.f;
  const f32x4 zz = {0.f, 0.f, 0.f, 0.f};

  for (int kstep = 0; kstep < nt; ++kstep) {
    float t0 = (float)kstep * h;
#pragma unroll 1
    for (int st = 0; st < 4; ++st) {
      float tin = t0 + ((st == 0) ? 0.f : (st == 3) ? h : 0.5f * h);

      // ---- S-build (both waves identical values; benign same-data write race)
      { float4 xv = {xin[0], xin[1], xin[2], xin[3]};
        *(float4*)(Yb + lr * 68 + lg * 4) = xv; }
      ldsfence();
      float4 s0 = *(const float4*)(Yb + lr * 68 + (lg & 1) * 8);
      float4 s1 = *(const float4*)(Yb + lr * 68 + (lg & 1) * 8 + 4);
      unsigned h0 = pk2(s0.x, s0.y), h1 = pk2(s0.z, s0.w);
      unsigned h2 = pk2(s1.x, s1.y), h3 = pk2(s1.z, s1.w);
      B8 sfO, sfG;
      if (lg < 2) {
        sfO.u[0] = h0; sfO.u[1] = h1; sfO.u[2] = h2; sfO.u[3] = h3;
        sfG.u[0] = h0; sfG.u[1] = h1; sfG.u[2] = h2; sfG.u[3] = h3;
      } else {
        float l0 = s0.x - __uint_as_float(h0 << 16);
        float l1 = s0.y - __uint_as_float(h0 & 0xffff0000u);
        float l2 = s0.z - __uint_as_float(h1 << 16);
        float l3 = s0.w - __uint_as_float(h1 & 0xffff0000u);
        float l4 = s1.x - __uint_as_float(h2 << 16);
        float l5 = s1.y - __uint_as_float(h2 & 0xffff0000u);
        float l6 = s1.z - __uint_as_float(h3 << 16);
        float l7 = s1.w - __uint_as_float(h3 & 0xffff0000u);
        sfO.u[0] = pk2(l0, l1); sfO.u[1] = pk2(l2, l3);
        sfO.u[2] = pk2(l4, l5); sfO.u[3] = pk2(l6, l7);
        if (lg == 2) { sfG.u[0] = pk2(tin, 1.f); sfG.u[1] = 0; sfG.u[2] = 0; sfG.u[3] = 0; }
        else { sfG.u[0] = 0; sfG.u[1] = 0; sfG.u[2] = 0; sfG.u[3] = 0; }
      }

      // ---- opening (own 2 row-blocks)
      f32x4 oA[2];
#pragma unroll
      for (int t = 0; t < 2; ++t) {
        oA[t] = MFMA(aK0h[t].v, sfO.v, zz, 0, 0, 0);
        oA[t] = MFMA(aK0l[t].v, sfO.v, oA[t], 0, 0, 0);
      }
      float cva[8];
#pragma unroll
      for (int t = 0; t < 2; ++t) {
        int mrow = (2 * wid + t) * 16;
        float4 b0v = *(const float4*)(b0s + mrow + lg * 4);
        float4 tcv = *(const float4*)(tcs + mrow + lg * 4);
        float4 u0v, cv4;
#pragma unroll
        for (int r = 0; r < 4; ++r) {
          float ov = oA[t][r] + fmaf(tin, ((const float*)&tcv)[r], ((const float*)&b0v)[r]);
          float e = __expf(-2.f * fabsf(ov));
          float rp = rcpf(1.f + e);
          float cm = (1.f - e) * rp;
          float c = __builtin_copysignf(cm, ov);
          cva[t * 4 + r] = c;
          ((float*)&u0v)[r] = fabsf(ov) + __logf(1.f + e);
          ((float*)&cv4)[r] = c;
        }
        *(float4*)(Xb + lr * 68 + mrow + lg * 4) = u0v;
        *(float4*)(csh + lr * 68 + mrow + lg * 4) = cv4;
      }
      __syncthreads();  // F1: u0, c ready

      // ---- feat1 (own 2 row-blocks; u0 from Xb full)
      B8 uf0, uf1;
      {
        const float* bp = Xb + lr * 68;
        float4 a0 = *(const float4*)(bp + lg * 8);
        float4 a1 = *(const float4*)(bp + lg * 8 + 4);
        float4 a2 = *(const float4*)(bp + 32 + lg * 8);
        float4 a3 = *(const float4*)(bp + 32 + lg * 8 + 4);
        uf0.u[0] = pk2(a0.x, a0.y); uf0.u[1] = pk2(a0.z, a0.w);
        uf0.u[2] = pk2(a1.x, a1.y); uf0.u[3] = pk2(a1.z, a1.w);
        uf1.u[0] = pk2(a2.x, a2.y); uf1.u[1] = pk2(a2.z, a2.w);
        uf1.u[2] = pk2(a3.x, a3.y); uf1.u[3] = pk2(a3.z, a3.w);
      }
      f32x4 fA[2];
#pragma unroll
      for (int t = 0; t < 2; ++t) {
        int mi = 2 * wid + t;
        fA[t] = MFMA(aK1[mi * 2].v, uf0.v, zz, 0, 0, 0);
        fA[t] = MFMA(aK1[mi * 2 + 1].v, uf1.v, fA[t], 0, 0, 0);
      }
#pragma unroll
      for (int t = 0; t < 2; ++t) {
        int mrow = (2 * wid + t) * 16;
        float4 b1v = *(const float4*)(b1s + mrow + lg * 4);
        float4 wv = *(const float4*)(wss + mrow + lg * 4);
        float4 av4, qv4;
#pragma unroll
        for (int r = 0; r < 4; ++r) {
          float fv = fA[t][r] + ((const float*)&b1v)[r];
          float e = __expf(-2.f * fabsf(fv));
          float rp = rcpf(1.f + e);
          float tf = __builtin_copysignf((1.f - e) * rp, fv);
          float wr = ((const float*)&wv)[r];
          ((float*)&av4)[r] = tf * wr;
          ((float*)&qv4)[r] = (1.f - tf * tf) * wr;
        }
        *(float4*)(Yb + lr * 68 + mrow + lg * 4) = av4;
        *(float4*)(qsh + lr * 68 + mrow + lg * 4) = qv4;
      }
      __syncthreads();  // F2: a, q ready

      // ---- z1 (own 2 row-blocks; a from Yb full) -> rv into Xb
      B8 af0, af1;
      {
        const float* bp = Yb + lr * 68;
        float4 a0 = *(const float4*)(bp + lg * 8);
        float4 a1 = *(const float4*)(bp + lg * 8 + 4);
        float4 a2 = *(const float4*)(bp + 32 + lg * 8);
        float4 a3 = *(const float4*)(bp + 32 + lg * 8 + 4);
        af0.u[0] = pk2(a0.x, a0.y); af0.u[1] = pk2(a0.z, a0.w);
        af0.u[2] = pk2(a1.x, a1.y); af0.u[3] = pk2(a1.z, a1.w);
        af1.u[0] = pk2(a2.x, a2.y); af1.u[1] = pk2(a2.z, a2.w);
        af1.u[2] = pk2(a3.x, a3.y); af1.u[3] = pk2(a3.z, a3.w);
      }
      f32x4 zA[2];
#pragma unroll
      for (int t = 0; t < 2; ++t) {
        zA[t] = MFMA(aK1T[t * 2].v, af0.v, zz, 0, 0, 0);
        zA[t] = MFMA(aK1T[t * 2 + 1].v, af1.v, zA[t], 0, 0, 0);
      }
      float trh_l = 0.f;
#pragma unroll
      for (int t = 0; t < 2; ++t) {
        int mrow = (2 * wid + t) * 16;
        float4 wv = *(const float4*)(wss + mrow + lg * 4);
        float4 kq = *(const float4*)(k0qs + mrow + lg * 4);
        float4 rv4;
#pragma unroll
        for (int r = 0; r < 4; ++r) {
          float c = cva[t * 4 + r];
          float z1v = zA[t][r] + ((const float*)&wv)[r];
          ((float*)&rv4)[r] = c * z1v;
          trh_l = fmaf((1.f - c * c) * z1v, ((const float*)&kq)[r], trh_l);
        }
        *(float4*)(Xb + lr * 68 + mrow + lg * 4) = rv4;
      }
      trh_l += __shfl_xor(trh_l, 16, 64);   // per-particle (lr) reduce over lg
      trh_l += __shfl_xor(trh_l, 32, 64);
      if (lane < 16) trhs[wid * 16 + lane] = trh_l;
      __syncthreads();  // F3: rv, trh halves ready

      // ---- KJ: own 8 particles; FULL-WAVE butterfly per particle (lr=i, lg=d here)
#pragma unroll 1
      for (int pi = 0; pi < 8; ++pi) {
        int p = wid * 8 + pi;
        const float* cp = csh + p * 68;
        float4 ca = *(const float4*)(cp + lg * 8);
        float4 cb = *(const float4*)(cp + lg * 8 + 4);
        float4 cc = *(const float4*)(cp + 32 + lg * 8);
        float4 cd = *(const float4*)(cp + 32 + lg * 8 + 4);
        B8 y0, y1;
        y0.u[0] = pk2(ca.x * kop[0],  ca.y * kop[1]);
        y0.u[1] = pk2(ca.z * kop[2],  ca.w * kop[3]);
        y0.u[2] = pk2(cb.x * kop[4],  cb.y * kop[5]);
        y0.u[3] = pk2(cb.z * kop[6],  cb.w * kop[7]);
        y1.u[0] = pk2(cc.x * kop[8],  cc.y * kop[9]);
        y1.u[1] = pk2(cc.z * kop[10], cc.w * kop[11]);
        y1.u[2] = pk2(cd.x * kop[12], cd.y * kop[13]);
        y1.u[3] = pk2(cd.z * kop[14], cd.w * kop[15]);
        f32x4 kc0 = MFMA(y0.v, aK1[0].v, zz, 0, 0, 0); kc0 = MFMA(y1.v, aK1[1].v, kc0, 0, 0, 0);
        f32x4 kc1 = MFMA(y0.v, aK1[2].v, zz, 0, 0, 0); kc1 = MFMA(y1.v, aK1[3].v, kc1, 0, 0, 0);
        f32x4 kc2 = MFMA(y0.v, aK1[4].v, zz, 0, 0, 0); kc2 = MFMA(y1.v, aK1[5].v, kc2, 0, 0, 0);
        f32x4 kc3 = MFMA(y0.v, aK1[6].v, zz, 0, 0, 0); kc3 = MFMA(y1.v, aK1[7].v, kc3, 0, 0, 0);
        float q0 = qsh[p * 68 + lr];
        float q1 = qsh[p * 68 + 16 + lr];
        float q2 = qsh[p * 68 + 32 + lr];
        float q3 = qsh[p * 68 + 48 + lr];
        float d0 = kc0[0] * kc0[0] + kc0[1] * kc0[1] + kc0[2] * kc0[2] + kc0[3] * kc0[3];
        float d1 = kc1[0] * kc1[0] + kc1[1] * kc1[1] + kc1[2] * kc1[2] + kc1[3] * kc1[3];
        float d2 = kc2[0] * kc2[0] + kc2[1] * kc2[1] + kc2[2] * kc2[2] + kc2[3] * kc2[3];
        float d3 = kc3[0] * kc3[0] + kc3[1] * kc3[1] + kc3[2] * kc3[2] + kc3[3] * kc3[3];
        float tp = q0 * d0 + q1 * d1 + q2 * d2 + q3 * d3;
#pragma unroll
        for (int off = 1; off < 64; off <<= 1) tp += __shfl_xor(tp, off, 64);
        if (lane == 0) tsh[p] = tp;
      }

      // ---- grad tile nb=wid: g = [rv; x; t; 1] x [K0 | symA | b]
      {
        B8 rf0, rf1;
        const float* bp = Xb + lr * 68;
        float4 a0 = *(const float4*)(bp + lg * 8);
        float4 a1 = *(const float4*)(bp + lg * 8 + 4);
        float4 a2 = *(const float4*)(bp + 32 + lg * 8);
        float4 a3 = *(const float4*)(bp + 32 + lg * 8 + 4);
        rf0.u[0] = pk2(a0.x, a0.y); rf0.u[1] = pk2(a0.z, a0.w);
        rf0.u[2] = pk2(a1.x, a1.y); rf0.u[3] = pk2(a1.z, a1.w);
        rf1.u[0] = pk2(a2.x, a2.y); rf1.u[1] = pk2(a2.z, a2.w);
        rf1.u[2] = pk2(a3.x, a3.y); rf1.u[3] = pk2(a3.z, a3.w);
        f32x4 g = MFMA(aG[0].v, rf0.v, zz, 0, 0, 0);
        g = MFMA(aG[1].v, rf1.v, g, 0, 0, 0);
        g = MFMA(aG[2].v, sfG.v, g, 0, 0, 0);
        if (wid == 0) {
          float4 gv = {g[0], g[1], g[2], g[3]};
          *(float4*)(gsh + lr * 20 + lg * 4) = gv;
        } else if (lane < 16) {
          gsh2[lane] = g[0];
        }
      }
      __syncthreads();  // F4: g0, g16, tsh ready

      // ---- RK4 update (replicated in both waves)
      float tsum = tsh[lr];
      float4 gv = *(const float4*)(gsh + lr * 20 + lg * 4);
      float kx[4];
      float dvp = 0.f;
#pragma unroll
      for (int r = 0; r < 4; ++r) {
        float d = -((const float*)&gv)[r];
        kx[r] = d; dvp = fmaf(d, d, dvp);
      }
      dvp += __shfl_xor(dvp, 16, 64);
      dvp += __shfl_xor(dvp, 32, 64);
      dvp *= 0.5f;
      float g16 = gsh2[lr];
      float trH = trhs[lr] + trhs[16 + lr] + tsum + sumA2;
      float dl = -trH;
      float dr = fabsf(dvp - g16);
      float wch = ((st == 0 || st == 3) ? (1.f / 6.f) : (1.f / 3.f)) * h;
#pragma unroll
      for (int r = 0; r < 4; ++r) xac[r] = fmaf(wch, kx[r], xac[r]);
      lacc = fmaf(wch, dl, lacc);
      vacc = fmaf(wch, dvp, vacc);
      racc = fmaf(wch, dr, racc);
      if (st < 3) {
        float anh = ((st == 2) ? 1.f : 0.5f) * h;
#pragma unroll
        for (int r = 0; r < 4; ++r) xin[r] = fmaf(anh, kx[r], x0s[r]);
      } else {
#pragma unroll
        for (int r = 0; r < 4; ++r) { x0s[r] = xac[r]; xin[r] = xac[r]; }
      }
    }
  }

  // ---- outputs (wave0: x; wave1: l/v/r)
  if (p0 + lr < n) {
    if (wid == 0) {
      float4 xa = {xac[0], xac[1], xac[2], xac[3]};
      *(float4*)(out + (size_t)(p0 + lr) * 16 + lg * 4) = xa;
    } else if (lg == 0) {
      out[(size_t)n * 16 + p0 + lr] = lacc;
      out[(size_t)n * 17 + p0 + lr] = vacc;
      out[(size_t)n * 18 + p0 + lr] = racc;
    }
  }
}

extern "C" void kernel_launch(void* const* d_in, const int* in_sizes, int n_in,
                              void* d_out, int out_size, void* d_ws, size_t ws_size,
                              hipStream_t stream) {
  const float* xg = (const float*)d_in[0];
  const float* wg = (const float*)d_in[1];
  const float* Ag = (const float*)d_in[2];
  const float* bg = (const float*)d_in[3];
  const float* K0g = (const float*)d_in[4];
  const float* b0g = (const float*)d_in[5];
  const float* K1g = (const float*)d_in[6];
  const float* b1g = (const float*)d_in[7];
  const int* ntg = (const int*)d_in[8];
  float* out = (float*)d_out;
  float* ws = (float*)d_ws;
  int n = in_sizes[0] / 16;

  hipLaunchKernelGGL(otflow_prep, dim3(1), dim3(256), 0, stream, K0g, Ag, ws);
  int nblk = (n + 15) / 16;
  hipLaunchKernelGGL(otflow_main, dim3(nblk), dim3(128), 0, stream,
                     xg, wg, bg, K0g, b0g, K1g, b1g, ntg, ws, out, n);
}